// Round 1
// baseline (444.762 us; speedup 1.0000x reference)
//
#include <hip/hip_runtime.h>

// ReconPhongIF: Phong shading with ray-marched shadows.
// Inputs (fp32): netA_out (32,5,256,256), netL_out (32,6),
//                recon_normal (32,3,256,256), recon_depth (32,1,256,256), light (32,2)
// Output (fp32): recon_im (32,3,256,256)
//
// Pipeline: [minred] per-batch min depth -> [shadow] 256-step ray march with
// provably-exact early exit (z monotonically decreasing; once z <= min(depth),
// bilinear sample (convex combo of depth) can never be < z) -> [compose]
// 7x7 gaussian blur of shadow mask + full Phong composition.
//
// Precision: shadow path uses fp contract(off) + IEEE div/sqrt + sequential
// pos accumulation to match XLA-CPU fp32 reference bit-for-bit (hard boolean
// boundary). Smooth paths (tanh/pow/blur) have large slack vs threshold.

#define SDIM 256
#define SS   (SDIM * SDIM)

// tan(10/360*pi) = tan(5 deg), double -> rounded to f32 at use sites
#define TAN_T 0.08748866352592401
// linspace(-1,1,256) step = 2/255 in f32
#define STEPC (2.0f / 255.0f)

__global__ __launch_bounds__(256) void minred_kernel(const float* __restrict__ depth,
                                                     float* __restrict__ mind) {
    const int b = blockIdx.x;
    const float* im = depth + (size_t)b * SS;
    float m = 3.4e38f;
    for (int idx = threadIdx.x; idx < SS; idx += 256) m = fminf(m, im[idx]);
    // wave64 reduce
    for (int off = 32; off > 0; off >>= 1) m = fminf(m, __shfl_down(m, off, 64));
    __shared__ float red[4];
    if ((threadIdx.x & 63) == 0) red[threadIdx.x >> 6] = m;
    __syncthreads();
    if (threadIdx.x == 0) {
        mind[b] = fminf(fminf(red[0], red[1]), fminf(red[2], red[3]));
    }
}

__global__ __launch_bounds__(256) void shadow_kernel(const float* __restrict__ depth,
                                                     const float* __restrict__ light,
                                                     const float* __restrict__ mind,
                                                     unsigned char* __restrict__ shmap) {
#pragma clang fp contract(off)
    const int j = threadIdx.x;   // column (W)
    const int i = blockIdx.x;    // row (H)
    const int b = blockIdx.y;

    const float* im = depth + (size_t)b * SS;
    const float T = (float)TAN_T;

    // light_d = normalize([lx, ly, 1])  (exact op order: lx*lx + ly*ly + 1, sqrt, div)
    const float lx = light[b * 2 + 0];
    const float ly = light[b * 2 + 1];
    float nrm2 = lx * lx;
    nrm2 = nrm2 + ly * ly;
    nrm2 = nrm2 + 1.0f;
    const float nrm = sqrtf(nrm2);
    const float ldx = lx / nrm;
    const float ldy = ly / nrm;
    const float ldz = 1.0f / nrm;
    const float sx = (-ldx) / 256.0f;   // step = -light_d / S (exact /2^8)
    const float sy = (-ldy) / 256.0f;
    const float sz = (-ldz) / 256.0f;

    // c[k] = (-1 + k*step) * t  (matches jnp.linspace then *t, fp32)
    const float cj = (-1.0f + (float)j * STEPC) * T;
    const float ci = (-1.0f + (float)i * STEPC) * T;

    const float d = im[i * SDIM + j];
    float px = cj * d;   // channel 0 ~ W coordinate
    float py = ci * d;   // channel 1 ~ H coordinate
    float pz = d;

    // early-exit floor: once pz <= min(depth)-1e-6, bilinear sample >= min(depth)
    // can never satisfy sampled - pz < 0 (1e-6 margin absorbs convex-sum rounding)
    const float mdv = mind[b] - 1e-6f;

    bool sh = false;
#pragma unroll 1
    for (int k = 0; k < SDIM; ++k) {
        px += sx; py += sy; pz += sz;
        const bool active = (!sh) && (pz > mdv);
        if (__ballot(active) == 0ull) break;
        if (active) {
            // pix = pos_xy / pos_z / t  (two IEEE divisions, as in reference)
            const float gx = (px / pz) / T;
            const float gy = (py / pz) / T;
            const float x = (gx + 1.0f) * 128.0f - 0.5f;
            const float y = (gy + 1.0f) * 128.0f - 0.5f;
            const float x0f = floorf(x);
            const float y0f = floorf(y);
            const float wx = x - x0f;
            const float wy = y - y0f;
            // clamp in float first (range-safe; <=-1 and >=256 classes are
            // invariant under this pre-clamp), then convert + border clamp
            const int x0 = (int)fminf(fmaxf(x0f, -300.0f), 300.0f);
            const int y0 = (int)fminf(fmaxf(y0f, -300.0f), 300.0f);
            const int x0c = min(max(x0, 0), SDIM - 1);
            const int x1c = min(max(x0 + 1, 0), SDIM - 1);
            const int y0c = min(max(y0, 0), SDIM - 1);
            const int y1c = min(max(y0 + 1, 0), SDIM - 1);
            const float v00 = im[y0c * SDIM + x0c];
            const float v01 = im[y0c * SDIM + x1c];
            const float v10 = im[y1c * SDIM + x0c];
            const float v11 = im[y1c * SDIM + x1c];
            // exact reference combine order
            float s = v00 * (1.0f - wx) * (1.0f - wy);
            s = s + v01 * wx * (1.0f - wy);
            s = s + v10 * (1.0f - wx) * wy;
            s = s + v11 * wx * wy;
            if (s - pz < 0.0f) sh = true;
        }
    }
    shmap[(size_t)b * SS + i * SDIM + j] = sh ? (unsigned char)1 : (unsigned char)0;
}

// normalized 1D gaussian (ksize=7, sigma=2), g/sum(g) computed in double:
__device__ __constant__ float W1[7] = {
    0.07015933f, 0.13107488f, 0.19071282f, 0.21610594f,
    0.19071282f, 0.13107488f, 0.07015933f
};

__global__ __launch_bounds__(256) void compose_kernel(const float* __restrict__ netA,
                                                      const float* __restrict__ netL,
                                                      const float* __restrict__ nrm,
                                                      const float* __restrict__ light,
                                                      const unsigned char* __restrict__ shmap,
                                                      float* __restrict__ out) {
    __shared__ float tile[22][23];  // 16+6 halo, +1 col pad

    const int b  = blockIdx.z;
    const int tx = threadIdx.x & 15;
    const int ty = threadIdx.x >> 4;
    const int j0 = blockIdx.x * 16;
    const int i0 = blockIdx.y * 16;

    // stage 22x22 shadow neighborhood (zero-padded SAME boundary)
    const unsigned char* shb = shmap + (size_t)b * SS;
    for (int idx = threadIdx.x; idx < 22 * 22; idx += 256) {
        const int r = idx / 22, c = idx - r * 22;
        const int gi = i0 - 3 + r, gj = j0 - 3 + c;
        float v = 0.0f;
        if (gi >= 0 && gi < SDIM && gj >= 0 && gj < SDIM) v = (float)shb[gi * SDIM + gj];
        tile[r][c] = v;
    }
    __syncthreads();

    const int i = i0 + ty;
    const int j = j0 + tx;

    // 7x7 separable gaussian blur of shadow mask
    float shadow_s = 0.0f;
    for (int dy = 0; dy < 7; ++dy) {
        float rs = 0.0f;
        for (int dx = 0; dx < 7; ++dx) rs += W1[dx] * tile[ty + dy][tx + dx];
        shadow_s += W1[dy] * rs;
    }

    // per-batch scalars
    const float l0 = tanhf(netL[b * 6 + 0]);
    const float l1 = tanhf(netL[b * 6 + 1]);
    const float l2 = tanhf(netL[b * 6 + 2]);
    const float l5 = tanhf(netL[b * 6 + 5]);
    const float e  = l0 * 0.5f + 0.5f;
    const float f  = e * (float)10.313708498984761 + 1.0f;  // sqrt(128)-1
    const float spec_alpha    = f * f;
    const float spec_strength = (l5 * 0.5f + 0.5f) * 0.5f;
    const float light_a = l1 / 2.0f + 0.5f;
    const float light_b = l2 / 2.0f + 0.5f;

    const float lx = light[b * 2 + 0];
    const float ly = light[b * 2 + 1];
    const float ln = sqrtf(lx * lx + ly * ly + 1.0f);
    const float ldx = lx / ln, ldy = ly / ln, ldz = 1.0f / ln;

    // view_d at (i,j) = normalize([x[255-j], x[255-i], 1])   (flip-after-normalize)
    const float T = (float)TAN_T;
    const float xsj = (-1.0f + (float)(SDIM - 1 - j) * STEPC) * T;
    const float xsi = (-1.0f + (float)(SDIM - 1 - i) * STEPC) * T;
    const float vn = sqrtf(xsj * xsj + xsi * xsi + 1.0f);
    const float vd0 = xsj / vn, vd1 = xsi / vn, vd2 = 1.0f / vn;

    const size_t pix = (size_t)i * SDIM + j;
    const float n0 = nrm[((size_t)(b * 3 + 0)) * SS + pix];
    const float n1 = nrm[((size_t)(b * 3 + 1)) * SS + pix];
    const float n2 = nrm[((size_t)(b * 3 + 2)) * SS + pix];

    const float cos_t  = n0 * ldx + n1 * ldy + n2 * ldz;
    const float diffuse = fmaxf(cos_t, 0.0f);

    const float r0 = 2.0f * cos_t * n0 - ldx;
    const float r1 = 2.0f * cos_t * n1 - ldy;
    const float r2 = 2.0f * cos_t * n2 - ldz;
    float spec = fmaxf(vd0 * r0 + vd1 * r1 + vd2 * r2, 0.0f);
    const float gate  = (cos_t > 0.0f) ? 1.0f : 0.0f;
    const float maskv = (i >= 5 && i < SDIM - 5 && j >= 5 && j < SDIM - 5) ? 1.0f : 0.0f;
    spec = spec * gate * maskv;
    const float sclip = fminf(fmaxf(spec, 1e-7f), (float)(1.0 - 1e-7));
    const float sshad = powf(sclip, spec_alpha);

    const float shadow_factor = fminf(fmaxf(1.0f - shadow_s, 0.1f), 1.0f);
    const float shading   = light_a + light_b * diffuse * shadow_factor;
    const float spec_term = spec_strength * light_b * sshad;

    const float inv_g = (float)(1.0 / 2.2);
#pragma unroll
    for (int c = 0; c < 3; ++c) {
        const float a   = netA[((size_t)(b * 5 + c)) * SS + pix];
        const float alb = powf(tanhf(a) / 2.0f + 0.5f, 2.2f);
        float rim = alb * shading + spec_term;
        rim = fmaxf(rim, 1e-7f);
        out[((size_t)(b * 3 + c)) * SS + pix] = powf(rim, inv_g);
    }
}

extern "C" void kernel_launch(void* const* d_in, const int* in_sizes, int n_in,
                              void* d_out, int out_size, void* d_ws, size_t ws_size,
                              hipStream_t stream) {
    const float* netA  = (const float*)d_in[0];  // (32,5,256,256)
    const float* netL  = (const float*)d_in[1];  // (32,6)
    const float* nrm   = (const float*)d_in[2];  // (32,3,256,256)
    const float* depth = (const float*)d_in[3];  // (32,1,256,256)
    const float* light = (const float*)d_in[4];  // (32,2)
    float* out = (float*)d_out;

    const int B = 32;
    float* mind = (float*)d_ws;                               // 32 floats
    unsigned char* shmap = (unsigned char*)d_ws + 256;        // B*S*S bytes = 2 MiB

    minred_kernel<<<B, 256, 0, stream>>>(depth, mind);
    shadow_kernel<<<dim3(SDIM, B), 256, 0, stream>>>(depth, light, mind, shmap);
    compose_kernel<<<dim3(SDIM / 16, SDIM / 16, B), 256, 0, stream>>>(netA, netL, nrm, light,
                                                                      shmap, out);
}

// Round 2
// 265.050 us; speedup vs baseline: 1.6780x; 1.6780x over previous
//
#include <hip/hip_runtime.h>

// ReconPhongIF: Phong shading with ray-marched shadows.
// R2: shadow march uses rcp+Newton fast path with GUARD-banded exact fallback
// (decision-identical to reference); minred split to 256 blocks; compose uses
// hw exp2/log2/rcp for pow/tanh (err ~1e-5 vs 2.2e-2 threshold slack).

#define SDIM 256
#define SS   (SDIM * SDIM)

// tan(10/360*pi) = tan(5 deg) in double; rounded to f32 at use sites
#define TAN_T 0.08748866352592401
// linspace(-1,1,256) step = 2/255 in f32
#define STEPC (2.0f / 255.0f)
// guard band for fast-vs-exact sign classification (worst-case fast-path
// error bound ~1.3e-4; 2.3x margin)
#define GUARD 3e-4f

// ---------------- stage 1: per-chunk min depth (256 blocks) ----------------
__global__ __launch_bounds__(256) void minred_kernel(const float* __restrict__ depth,
                                                     float* __restrict__ pmin) {
    const int blk = blockIdx.x;  // chunk index; batch b = blk>>3
    const float4* p = (const float4*)(depth + (size_t)blk * 8192);
    float m = 3.4e38f;
#pragma unroll
    for (int i = 0; i < 8; ++i) {
        const float4 v = p[threadIdx.x + i * 256];
        m = fminf(m, fminf(fminf(v.x, v.y), fminf(v.z, v.w)));
    }
    for (int off = 32; off > 0; off >>= 1) m = fminf(m, __shfl_down(m, off, 64));
    __shared__ float red[4];
    if ((threadIdx.x & 63) == 0) red[threadIdx.x >> 6] = m;
    __syncthreads();
    if (threadIdx.x == 0) pmin[blk] = fminf(fminf(red[0], red[1]), fminf(red[2], red[3]));
}

// ---------------- stage 2: ray-marched shadow ----------------
__global__ __launch_bounds__(256) void shadow_kernel(const float* __restrict__ depth,
                                                     const float* __restrict__ light,
                                                     const float* __restrict__ pmin,
                                                     unsigned char* __restrict__ shmap) {
#pragma clang fp contract(off)
    const int j = threadIdx.x;   // column (W)
    const int i = blockIdx.x;    // row (H)
    const int b = blockIdx.y;

    const float* im = depth + (size_t)b * SS;
    const float T = (float)TAN_T;
    const float K = (float)(128.0 / TAN_T);  // fast-path scale

    // light_d = normalize([lx, ly, 1])  (exact reference op order)
    const float lx = light[b * 2 + 0];
    const float ly = light[b * 2 + 1];
    float nrm2 = lx * lx;
    nrm2 = nrm2 + ly * ly;
    nrm2 = nrm2 + 1.0f;
    const float nrm = sqrtf(nrm2);
    const float ldx = lx / nrm;
    const float ldy = ly / nrm;
    const float ldz = 1.0f / nrm;
    const float sx = (-ldx) / 256.0f;
    const float sy = (-ldy) / 256.0f;
    const float sz = (-ldz) / 256.0f;

    // per-batch min depth from 8 partials (uniform -> scalar loads)
    float md = pmin[b * 8 + 0];
    for (int c = 1; c < 8; ++c) md = fminf(md, pmin[b * 8 + c]);
    const float mdv = md - 1e-6f;  // early-exit floor (provably exact)

    const float cj = (-1.0f + (float)j * STEPC) * T;
    const float ci = (-1.0f + (float)i * STEPC) * T;

    const float d = im[i * SDIM + j];
    float px = cj * d;
    float py = ci * d;
    float pz = d;

    bool sh = false;
#pragma unroll 1
    for (int k = 0; k < SDIM; ++k) {
        px += sx; py += sy; pz += sz;
        const bool active = (!sh) && (pz > mdv);
        if (__ballot(active) == 0ull) break;
        if (active) {
            // ---- fast path: rcp + newton (rel err ~2e-7) ----
            float inv = __builtin_amdgcn_rcpf(pz);
            inv = fmaf(fmaf(-pz, inv, 1.0f), inv, inv);
            const float xf = fmaf(px * inv, K, 127.5f);
            const float yf = fmaf(py * inv, K, 127.5f);
            const float x0ff = floorf(xf);
            const float y0ff = floorf(yf);
            const float wxf = xf - x0ff;
            const float wyf = yf - y0ff;
            const int x0 = (int)fminf(fmaxf(x0ff, -300.0f), 300.0f);
            const int y0 = (int)fminf(fmaxf(y0ff, -300.0f), 300.0f);
            const int x0c = min(max(x0, 0), SDIM - 1);
            const int x1c = min(max(x0 + 1, 0), SDIM - 1);
            const int y0c = min(max(y0, 0), SDIM - 1);
            const int y1c = min(max(y0 + 1, 0), SDIM - 1);
            const int r0 = y0c << 8, r1 = y1c << 8;
            const float v00 = im[r0 + x0c];
            const float v01 = im[r0 + x1c];
            const float v10 = im[r1 + x0c];
            const float v11 = im[r1 + x1c];
            const float omx = 1.0f - wxf;
            const float omy = 1.0f - wyf;
            const float t0 = fmaf(v01, wxf, v00 * omx);
            const float t1 = fmaf(v11, wxf, v10 * omx);
            const float sF = fmaf(t1, wyf, t0 * omy);
            const float diff = sF - pz;
            bool shf = diff < 0.0f;
            if (__builtin_expect(fabsf(diff) <= GUARD, 0)) {
                // ---- exact fallback: bit-identical to reference ----
                const float gx = (px / pz) / T;
                const float gy = (py / pz) / T;
                const float x = (gx + 1.0f) * 128.0f - 0.5f;
                const float y = (gy + 1.0f) * 128.0f - 0.5f;
                const float x0f = floorf(x);
                const float y0f = floorf(y);
                const float wx = x - x0f;
                const float wy = y - y0f;
                const int ex0 = (int)fminf(fmaxf(x0f, -300.0f), 300.0f);
                const int ey0 = (int)fminf(fmaxf(y0f, -300.0f), 300.0f);
                const int ex0c = min(max(ex0, 0), SDIM - 1);
                const int ex1c = min(max(ex0 + 1, 0), SDIM - 1);
                const int ey0c = min(max(ey0, 0), SDIM - 1);
                const int ey1c = min(max(ey0 + 1, 0), SDIM - 1);
                const float e00 = im[ey0c * SDIM + ex0c];
                const float e01 = im[ey0c * SDIM + ex1c];
                const float e10 = im[ey1c * SDIM + ex0c];
                const float e11 = im[ey1c * SDIM + ex1c];
                float s = e00 * (1.0f - wx) * (1.0f - wy);
                s = s + e01 * wx * (1.0f - wy);
                s = s + e10 * (1.0f - wx) * wy;
                s = s + e11 * wx * wy;
                shf = (s - pz) < 0.0f;
            }
            sh = sh || shf;
        }
    }
    shmap[(size_t)b * SS + i * SDIM + j] = sh ? (unsigned char)1 : (unsigned char)0;
}

// ---------------- stage 3: blur + Phong composition ----------------
__device__ __constant__ float W1[7] = {
    0.07015933f, 0.13107488f, 0.19071282f, 0.21610594f,
    0.19071282f, 0.13107488f, 0.07015933f
};

__device__ __forceinline__ float fpow(float x, float p) {
    // x > 0 required; err ~1e-6 rel (v_log/v_exp are ~1ulp)
    return __builtin_amdgcn_exp2f(p * __builtin_amdgcn_logf(x));
}
__device__ __forceinline__ float ftanh(float x) {
    // tanh(x) = (e^{2x}-1)/(e^{2x}+1); 2*log2(e) = 2.88539008...
    const float e = __builtin_amdgcn_exp2f(x * 2.8853900817779268f);
    return (e - 1.0f) * __builtin_amdgcn_rcpf(e + 1.0f);
}

__global__ __launch_bounds__(256) void compose_kernel(const float* __restrict__ netA,
                                                      const float* __restrict__ netL,
                                                      const float* __restrict__ nrm,
                                                      const float* __restrict__ light,
                                                      const unsigned char* __restrict__ shmap,
                                                      float* __restrict__ out) {
    __shared__ float tile[22][23];  // 16+6 halo, +1 col pad

    const int b  = blockIdx.z;
    const int tx = threadIdx.x & 15;
    const int ty = threadIdx.x >> 4;
    const int j0 = blockIdx.x * 16;
    const int i0 = blockIdx.y * 16;

    const unsigned char* shb = shmap + (size_t)b * SS;
    for (int idx = threadIdx.x; idx < 22 * 22; idx += 256) {
        const int r = idx / 22, c = idx - r * 22;
        const int gi = i0 - 3 + r, gj = j0 - 3 + c;
        float v = 0.0f;
        if (gi >= 0 && gi < SDIM && gj >= 0 && gj < SDIM) v = (float)shb[gi * SDIM + gj];
        tile[r][c] = v;
    }
    __syncthreads();

    const int i = i0 + ty;
    const int j = j0 + tx;

    float shadow_s = 0.0f;
#pragma unroll
    for (int dy = 0; dy < 7; ++dy) {
        float rs = 0.0f;
#pragma unroll
        for (int dx = 0; dx < 7; ++dx) rs += W1[dx] * tile[ty + dy][tx + dx];
        shadow_s += W1[dy] * rs;
    }

    // per-batch scalars (uniform -> scalar path); keep precise tanhf here
    const float l0 = tanhf(netL[b * 6 + 0]);
    const float l1 = tanhf(netL[b * 6 + 1]);
    const float l2 = tanhf(netL[b * 6 + 2]);
    const float l5 = tanhf(netL[b * 6 + 5]);
    const float e  = l0 * 0.5f + 0.5f;
    const float f  = e * (float)10.313708498984761 + 1.0f;  // sqrt(128)-1
    const float spec_alpha    = f * f;
    const float spec_strength = (l5 * 0.5f + 0.5f) * 0.5f;
    const float light_a = l1 / 2.0f + 0.5f;
    const float light_b = l2 / 2.0f + 0.5f;

    const float lx = light[b * 2 + 0];
    const float ly = light[b * 2 + 1];
    const float ln = sqrtf(lx * lx + ly * ly + 1.0f);
    const float ldx = lx / ln, ldy = ly / ln, ldz = 1.0f / ln;

    const float T = (float)TAN_T;
    const float xsj = (-1.0f + (float)(SDIM - 1 - j) * STEPC) * T;
    const float xsi = (-1.0f + (float)(SDIM - 1 - i) * STEPC) * T;
    const float vn = sqrtf(xsj * xsj + xsi * xsi + 1.0f);
    const float vd0 = xsj / vn, vd1 = xsi / vn, vd2 = 1.0f / vn;

    const size_t pix = (size_t)i * SDIM + j;
    const float n0 = nrm[((size_t)(b * 3 + 0)) * SS + pix];
    const float n1 = nrm[((size_t)(b * 3 + 1)) * SS + pix];
    const float n2 = nrm[((size_t)(b * 3 + 2)) * SS + pix];

    const float cos_t   = n0 * ldx + n1 * ldy + n2 * ldz;
    const float diffuse = fmaxf(cos_t, 0.0f);

    const float r0 = 2.0f * cos_t * n0 - ldx;
    const float r1 = 2.0f * cos_t * n1 - ldy;
    const float r2 = 2.0f * cos_t * n2 - ldz;
    float spec = fmaxf(vd0 * r0 + vd1 * r1 + vd2 * r2, 0.0f);
    const float gate  = (cos_t > 0.0f) ? 1.0f : 0.0f;
    const float maskv = (i >= 5 && i < SDIM - 5 && j >= 5 && j < SDIM - 5) ? 1.0f : 0.0f;
    spec = spec * gate * maskv;
    const float sclip = fminf(fmaxf(spec, 1e-7f), (float)(1.0 - 1e-7));
    const float sshad = fpow(sclip, spec_alpha);

    const float shadow_factor = fminf(fmaxf(1.0f - shadow_s, 0.1f), 1.0f);
    const float shading   = light_a + light_b * diffuse * shadow_factor;
    const float spec_term = spec_strength * light_b * sshad;

    const float inv_g = (float)(1.0 / 2.2);
#pragma unroll
    for (int c = 0; c < 3; ++c) {
        const float a   = netA[((size_t)(b * 5 + c)) * SS + pix];
        const float alb = fpow(ftanh(a) * 0.5f + 0.5f, 2.2f);
        float rim = alb * shading + spec_term;
        rim = fmaxf(rim, 1e-7f);
        out[((size_t)(b * 3 + c)) * SS + pix] = fpow(rim, inv_g);
    }
}

extern "C" void kernel_launch(void* const* d_in, const int* in_sizes, int n_in,
                              void* d_out, int out_size, void* d_ws, size_t ws_size,
                              hipStream_t stream) {
    const float* netA  = (const float*)d_in[0];  // (32,5,256,256)
    const float* netL  = (const float*)d_in[1];  // (32,6)
    const float* nrm   = (const float*)d_in[2];  // (32,3,256,256)
    const float* depth = (const float*)d_in[3];  // (32,1,256,256)
    const float* light = (const float*)d_in[4];  // (32,2)
    float* out = (float*)d_out;

    const int B = 32;
    float* pmin = (float*)d_ws;                          // 256 floats (8 per batch)
    unsigned char* shmap = (unsigned char*)d_ws + 1024;  // B*S*S bytes = 2 MiB

    minred_kernel<<<B * 8, 256, 0, stream>>>(depth, pmin);
    shadow_kernel<<<dim3(SDIM, B), 256, 0, stream>>>(depth, light, pmin, shmap);
    compose_kernel<<<dim3(SDIM / 16, SDIM / 16, B), 256, 0, stream>>>(netA, netL, nrm, light,
                                                                      shmap, out);
}